// Round 9
// baseline (2316.085 us; speedup 1.0000x reference)
//
#include <hip/hip_runtime.h>

// ---------------- problem constants ----------------
constexpr int B_ = 256;        // batch
constexpr int K_ = 6144;       // block length
constexpr int NITER = 6;
constexpr int L_ = 6;          // window valid length
constexpr int W0_ = 32;        // uniform-init warmup (iteration 0)
constexpr int C_ = K_ / L_;    // chunks = 1024 blocks = 4/CU exactly
constexpr float LOG2E = 1.4426950408889634f;
constexpr float LN2   = 0.6931471805599453f;

static_assert(K_ % L_ == 0, "");
static_assert((L_ % 2) == 0 && (W0_ % 2) == 0, "");
static_assert(C_ == 1024, "grid must equal 4 blocks/CU * 256 CUs for barrier");

#if __has_builtin(__builtin_amdgcn_exp2f)
#define EXP2F(x) __builtin_amdgcn_exp2f(x)
#else
#define EXP2F(x) exp2f(x)
#endif
#if __has_builtin(__builtin_amdgcn_logf)
#define LOG2F(x) __builtin_amdgcn_logf(x)
#else
#define LOG2F(x) log2f(x)
#endif
#if __has_builtin(__builtin_amdgcn_rcpf)
#define RCPF(x) __builtin_amdgcn_rcpf(x)
#else
#define RCPF(x) (1.0f / (x))
#endif

typedef unsigned short ushort_t;

// trellis: fb(s,u)=u^s1^s0, nxt(s,u)=(fb<<2)|(s>>1), par(s,u)=u^s1^s2
// Linear-domain with normalized gammas: ghat[u][p] = A_u*B_p, A={1,es} by
// sign of gx (es=2^-|gx|), B likewise (ep=2^-|gy|). Common scale cancels in
// the posterior ratio and renormalized alpha/beta -> equivalent to log-MAP.

__device__ __forceinline__ void gam_lin(float gxv, float gyv, float g[4]) {
  float es = EXP2F(-fabsf(gxv));
  float ep = EXP2F(-fabsf(gyv));
  float fu0 = gxv >= 0.0f ? 1.0f : es;
  float fu1 = gxv >= 0.0f ? es : 1.0f;
  float fp0 = gyv >= 0.0f ? 1.0f : ep;
  float fp1 = gyv >= 0.0f ? ep : 1.0f;
  g[0] = fu0 * fp0; g[1] = fu0 * fp1;
  g[2] = fu1 * fp0; g[3] = fu1 * fp1;
}

__device__ __forceinline__ void step_fwd_lin(float a[8], const float g[4]) {
  float an[8];
#pragma unroll
  for (int sn = 0; sn < 8; ++sn) {
    const int u0 = ((sn >> 2) ^ (sn & 1)) & 1;
    const int p0 = ((sn >> 2) ^ ((sn >> 1) & 1)) & 1;
    an[sn] = a[(sn & 3) * 2] * g[u0 * 2 + p0]
           + a[(sn & 3) * 2 + 1] * g[(u0 ^ 1) * 2 + (p0 ^ 1)];
  }
#pragma unroll
  for (int s = 0; s < 8; ++s) a[s] = an[s];
}

__device__ __forceinline__ void step_bwd_lin(float bt[8], const float g[4]) {
  float bn[8];
#pragma unroll
  for (int s = 0; s < 8; ++s) {
    const int s0 = s & 1, s1b = (s >> 1) & 1, s2b = (s >> 2) & 1;
    const int f0 = s1b ^ s0, q = s1b ^ s2b;
    bn[s] = g[q] * bt[(f0 << 2) | (s >> 1)]
          + g[2 + (q ^ 1)] * bt[((f0 ^ 1) << 2) | (s >> 1)];
  }
#pragma unroll
  for (int s = 0; s < 8; ++s) bt[s] = bn[s];
}

// max-renorm with tiny floor injection: NaN/underflow-proof
__device__ __forceinline__ void renorm_lin(float a[8]) {
  float m = fmaxf(fmaxf(fmaxf(a[0], a[1]), fmaxf(a[2], a[3])),
                  fmaxf(fmaxf(a[4], a[5]), fmaxf(a[6], a[7])));
  float r = RCPF(fmaxf(m, 1e-30f));
#pragma unroll
  for (int s = 0; s < 8; ++s) a[s] = fmaf(a[s], r, 1e-32f);
}

// ---- bf16-packed boundary states (renormalized probs in [1e-32,1]) ------
__device__ __forceinline__ void store8_bf16(ushort_t* p, const float a[8]) {
  unsigned int us[8];
#pragma unroll
  for (int s = 0; s < 8; ++s) {
    unsigned int u = __float_as_uint(a[s]);
    u += 0x7FFFu + ((u >> 16) & 1u);       // round-to-nearest-even
    us[s] = u >> 16;
  }
  uint4 v;
  v.x = us[0] | (us[1] << 16);
  v.y = us[2] | (us[3] << 16);
  v.z = us[4] | (us[5] << 16);
  v.w = us[6] | (us[7] << 16);
  *(uint4*)p = v;
}

__device__ __forceinline__ void load8_bf16(const ushort_t* p, float a[8]) {
  uint4 v = *(const uint4*)p;
  a[0] = __uint_as_float(v.x << 16);
  a[1] = __uint_as_float(v.x & 0xFFFF0000u);
  a[2] = __uint_as_float(v.y << 16);
  a[3] = __uint_as_float(v.y & 0xFFFF0000u);
  a[4] = __uint_as_float(v.z << 16);
  a[5] = __uint_as_float(v.z & 0xFFFF0000u);
  a[6] = __uint_as_float(v.w << 16);
  a[7] = __uint_as_float(v.w & 0xFFFF0000u);
}

// ---------------- grid barrier (all blocks co-resident by construction) ---
__device__ __forceinline__ void gbar(unsigned* cnt, unsigned* gen, unsigned nb) {
  __syncthreads();
  if (threadIdx.x == 0) {
    __threadfence();   // agent-scope release of this block's prior writes
    unsigned g = __hip_atomic_load(gen, __ATOMIC_ACQUIRE,
                                   __HIP_MEMORY_SCOPE_AGENT);
    unsigned t = __hip_atomic_fetch_add(cnt, 1u, __ATOMIC_ACQ_REL,
                                        __HIP_MEMORY_SCOPE_AGENT);
    if (t == nb - 1u) {
      __hip_atomic_store(cnt, 0u, __ATOMIC_RELAXED, __HIP_MEMORY_SCOPE_AGENT);
      __hip_atomic_fetch_add(gen, 1u, __ATOMIC_RELEASE,
                             __HIP_MEMORY_SCOPE_AGENT);
    } else {
      while (__hip_atomic_load(gen, __ATOMIC_ACQUIRE,
                               __HIP_MEMORY_SCOPE_AGENT) == g) {
        __builtin_amdgcn_s_sleep(1);
      }
    }
    __threadfence();   // agent-scope acquire for the block
  }
  __syncthreads();
}

// ---------------- one windowed BCJR half-iteration (linear domain) --------
// wmode 0: uniform warmup W0 (it 0); wmode 1: NII boundary state + L_ warmup
// steps; wmode 2: pure inheritance. S[c]=alpha at c*L_ (bf16); T[c]=beta.
// mode 0: scatter extrinsic into other decoder's gx; mode 1: write lpost.
__device__ __forceinline__ void half_body(const float* __restrict__ gx,
                                          const float* __restrict__ gy,
                                          const float* __restrict__ lsother,
                                          const int* __restrict__ map,
                                          float* __restrict__ gxother,
                                          float* __restrict__ lpost_out,
                                          const ushort_t* __restrict__ Sread,
                                          ushort_t* __restrict__ Swrite,
                                          const ushort_t* __restrict__ Tread,
                                          ushort_t* __restrict__ Twrite,
                                          int wmode, int mode, int c, int b) {
  const int kv = c * L_;
  const int kend = kv + L_;

  // valid-region gamma: load + convert to linear scaled table (cached)
  float gvx[L_];        // log2-domain lsu (needed for extrinsic)
  float gc[L_][4];      // linear scaled gamma table
#pragma unroll
  for (int i = 0; i < L_; ++i) {
    size_t o = (size_t)(kv + i) * B_ + b;
    float x = gx[o], y = gy[o];
    gvx[i] = x;
    gam_lin(x, y, gc[i]);
  }

  // ---------------- forward ----------------
  float a[8];
  if (c == 0) {
    a[0] = 1.0f;
#pragma unroll
    for (int s = 1; s < 8; ++s) a[s] = 0.0f;
  } else if (wmode == 0) {
    int wu = kv < W0_ ? kv : W0_;
    if (kv <= W0_) {                 // warmup reaches position 0: exact init
      a[0] = 1.0f;
#pragma unroll
      for (int s = 1; s < 8; ++s) a[s] = 0.0f;
    } else {
#pragma unroll
      for (int s = 0; s < 8; ++s) a[s] = 1.0f;
    }
    int n = wu, k = kv - wu;
    float cx0, cy0, cx1, cy1;
    if (n > 0) {
      size_t o0 = (size_t)k * B_ + b, o1 = (size_t)(k + 1) * B_ + b;
      cx0 = gx[o0]; cy0 = gy[o0]; cx1 = gx[o1]; cy1 = gy[o1];
    }
    while (n > 0) {
      float nx0, ny0, nx1, ny1;
      if (n > 2) {
        size_t o0 = (size_t)(k + 2) * B_ + b, o1 = (size_t)(k + 3) * B_ + b;
        nx0 = gx[o0]; ny0 = gy[o0]; nx1 = gx[o1]; ny1 = gy[o1];
      }
      float g[4];
      gam_lin(cx0, cy0, g); step_fwd_lin(a, g);
      gam_lin(cx1, cy1, g); step_fwd_lin(a, g);
      renorm_lin(a);
      if (n > 2) { cx0 = nx0; cy0 = ny0; cx1 = nx1; cy1 = ny1; }
      k += 2; n -= 2;
    }
  } else if (wmode == 1) {
    // NII: prev-iter alpha at kv - L_, refreshed by L_ warmup steps.
    float wx[L_], wy[L_];
#pragma unroll
    for (int q = 0; q < L_; ++q) {
      size_t o = (size_t)(kv - L_ + q) * B_ + b;
      wx[q] = gx[o]; wy[q] = gy[o];
    }
    if (c == 1) {                    // warmup starts at position 0: exact init
      a[0] = 1.0f;
#pragma unroll
      for (int s = 1; s < 8; ++s) a[s] = 0.0f;
    } else {
      load8_bf16(&Sread[((size_t)(c - 1) * B_ + b) * 8], a);
    }
#pragma unroll
    for (int q = 0; q < L_; ++q) {
      float g[4];
      gam_lin(wx[q], wy[q], g);
      step_fwd_lin(a, g);
      if (q & 1) renorm_lin(a);
    }
  } else {
    load8_bf16(&Sread[((size_t)c * B_ + b) * 8], a);  // pure inheritance
  }
  // valid region: record alpha, then step (all L steps -> a = alpha(kend))
  float a2d[L_][8];
#pragma unroll
  for (int i = 0; i < L_; ++i) {
#pragma unroll
    for (int s = 0; s < 8; ++s) a2d[i][s] = a[s];
    step_fwd_lin(a, gc[i]);
    if (i & 1) renorm_lin(a);
  }
  store8_bf16(&Swrite[((size_t)(c + 1) * B_ + b) * 8], a);

  // ---------------- backward + posterior ----------------
  float bt[8];
  if (c == C_ - 1) {
#pragma unroll
    for (int s = 0; s < 8; ++s) bt[s] = 1.0f;    // exact tail init (uniform)
  } else if (wmode == 0) {
    int rem = K_ - kend;
    int wub = rem < W0_ ? rem : W0_;
#pragma unroll
    for (int s = 0; s < 8; ++s) bt[s] = 1.0f;
    int n = wub, k = kend + wub - 1;
    float cx0, cy0, cx1, cy1;
    if (n > 0) {
      size_t o0 = (size_t)k * B_ + b, o1 = (size_t)(k - 1) * B_ + b;
      cx0 = gx[o0]; cy0 = gy[o0]; cx1 = gx[o1]; cy1 = gy[o1];
    }
    while (n > 0) {
      float nx0, ny0, nx1, ny1;
      if (n > 2) {
        size_t o0 = (size_t)(k - 2) * B_ + b, o1 = (size_t)(k - 3) * B_ + b;
        nx0 = gx[o0]; ny0 = gy[o0]; nx1 = gx[o1]; ny1 = gy[o1];
      }
      float g[4];
      gam_lin(cx0, cy0, g); step_bwd_lin(bt, g);
      gam_lin(cx1, cy1, g); step_bwd_lin(bt, g);
      renorm_lin(bt);
      if (n > 2) { cx0 = nx0; cy0 = ny0; cx1 = nx1; cy1 = ny1; }
      k -= 2; n -= 2;
    }
  } else if (wmode == 1) {
    float wx[L_], wy[L_];
#pragma unroll
    for (int q = 0; q < L_; ++q) {
      size_t o = (size_t)(kend + L_ - 1 - q) * B_ + b;
      wx[q] = gx[o]; wy[q] = gy[o];
    }
    if (c >= C_ - 2) {                // warmup start >= K_: uniform is exact
#pragma unroll
      for (int s = 0; s < 8; ++s) bt[s] = 1.0f;
    } else {
      load8_bf16(&Tread[((size_t)(c + 2) * B_ + b) * 8], bt);
    }
#pragma unroll
    for (int q = 0; q < L_; ++q) {
      float g[4];
      gam_lin(wx[q], wy[q], g);
      step_bwd_lin(bt, g);
      if (q & 1) renorm_lin(bt);
    }
  } else {
    load8_bf16(&Tread[((size_t)(c + 1) * B_ + b) * 8], bt);  // inheritance
  }
  // valid region, descending: posterior + extrinsic + beta step
#pragma unroll
  for (int ii = 0; ii < L_; ++ii) {
    const int i = L_ - 1 - ii;
    const int kk = kv + i;
    const float* g = gc[i];
    float s00 = 0.0f, s01 = 0.0f, s10 = 0.0f, s11 = 0.0f;
    float bn[8];
#pragma unroll
    for (int s = 0; s < 8; ++s) {
      const int s0 = s & 1, s1b = (s >> 1) & 1, s2b = (s >> 2) & 1;
      const int f0 = s1b ^ s0, q = s1b ^ s2b;
      float b0 = bt[(f0 << 2) | (s >> 1)];
      float b1 = bt[((f0 ^ 1) << 2) | (s >> 1)];
      float m0 = a2d[i][s] * b0;
      float m1 = a2d[i][s] * b1;
      if (q == 0) { s00 += m0; s10 += m1; } else { s01 += m0; s11 += m1; }
      bn[s] = g[q] * b0 + g[2 + (q ^ 1)] * b1;
    }
    float t0 = g[0] * s00 + g[1] * s01;
    float t1 = g[3] * s10 + g[2] * s11;
    float lpost = LOG2F(fmaxf(t0, 1e-37f)) - LOG2F(fmaxf(t1, 1e-37f));
    if (mode == 0) {
      float le = lpost - gvx[i];               // lpost - (ls + la)
      const int j = map[kk];
      const size_t oo = (size_t)j * B_ + b;
      gxother[oo] = lsother[oo] + le;
    } else {
      lpost_out[(size_t)kk * B_ + b] = lpost;
    }
#pragma unroll
    for (int s = 0; s < 8; ++s) bt[s] = bn[s];
    if (ii & 1) renorm_lin(bt);
  }
  store8_bf16(&Twrite[((size_t)c * B_ + b) * 8], bt);
}

// ---------------- fused persistent kernel: all 12 half-iterations ---------
__global__ __launch_bounds__(256, 4) void k_fused(
    float* __restrict__ gx1, float* __restrict__ gy1,
    float* __restrict__ gx2, float* __restrict__ gy2,
    const float* __restrict__ ls1, const float* __restrict__ ls2,
    const int* __restrict__ perm, const int* __restrict__ inv,
    float* __restrict__ lpost2t,
    ushort_t* S1a, ushort_t* S1b, ushort_t* T1a, ushort_t* T1b,
    ushort_t* S2a, ushort_t* S2b, ushort_t* T2a, ushort_t* T2b,
    unsigned* cnt, unsigned* gen) {
  const int c = blockIdx.x;
  const int b = threadIdx.x;
  for (int ph = 0; ph < 2 * NITER; ++ph) {
    const int it = ph >> 1, half = ph & 1;
    const int wm = (it == 0) ? 0 : (it <= 3 ? 1 : 2);
    const int md = (ph == 2 * NITER - 1) ? 1 : 0;
    const int pr = it & 1;
    const float* pgx = half ? gx2 : gx1;
    const float* pgy = half ? gy2 : gy1;
    const float* pls = half ? ls1 : ls2;
    const int* pmap  = half ? perm : inv;
    float* pgxo      = half ? gx1 : gx2;
    const ushort_t* Sr = half ? (pr ? S2b : S2a) : (pr ? S1b : S1a);
    ushort_t* Sw       = half ? (pr ? S2a : S2b) : (pr ? S1a : S1b);
    const ushort_t* Tr = half ? (pr ? T2b : T2a) : (pr ? T1b : T1a);
    ushort_t* Tw       = half ? (pr ? T2a : T2b) : (pr ? T1a : T1b);
    half_body(pgx, pgy, pls, pmap, pgxo, lpost2t, Sr, Sw, Tr, Tw,
              wm, md, c, b);
    if (ph != 2 * NITER - 1) gbar(cnt, gen, (unsigned)gridDim.x);
  }
}

// ---------------- prep: de-interleave + transpose + scale to log2 domain --
__global__ __launch_bounds__(256) void k_prep1(const float* __restrict__ inp,
                                               float* __restrict__ ls1,
                                               float* __restrict__ gx1,
                                               float* __restrict__ gy1,
                                               float* __restrict__ gy2) {
  __shared__ float t[3][64][65];
  const int tid = threadIdx.x;
  const int k0 = blockIdx.x * 64, b0 = blockIdx.y * 64;
  const int tk = tid & 63, tq = tid >> 6;
  for (int bb = tq; bb < 64; bb += 4) {
    size_t base = (size_t)(b0 + bb) * (3 * K_) + 3 * (size_t)(k0 + tk);
    t[0][bb][tk] = inp[base + 0];
    t[1][bb][tk] = inp[base + 1];
    t[2][bb][tk] = inp[base + 2];
  }
  __syncthreads();
  const int tb = tid & 63, kq = tid >> 6;
  for (int kk = kq; kk < 64; kk += 4) {
    size_t o = (size_t)(k0 + kk) * B_ + (b0 + tb);
    float sv = -LOG2E * t[0][tb][kk];
    float p1 = -LOG2E * t[1][tb][kk];
    float p2 = -LOG2E * t[2][tb][kk];
    ls1[o] = sv;
    gx1[o] = sv;          // la=0 initially -> lsu = ls
    gy1[o] = p1;
    gy2[o] = p2;
  }
}

__global__ __launch_bounds__(256) void k_prep2(const float* __restrict__ ls1,
                                               const int* __restrict__ perm,
                                               float* __restrict__ ls2,
                                               int* __restrict__ inv) {
  const int j = blockIdx.x;
  const int b = threadIdx.x;
  const int p = perm[j];
  ls2[(size_t)j * B_ + b] = ls1[(size_t)p * B_ + b];
  if (b == 0) inv[p] = j;
}

// ---------------- output: out[b,i] = -ln2 * lpost2'[inv[i], b] ------------
__global__ __launch_bounds__(256) void k_out(const float* __restrict__ lpost2t,
                                             const int* __restrict__ inv,
                                             float* __restrict__ out) {
  __shared__ float t[64][65];
  const int tid = threadIdx.x;
  const int i0 = blockIdx.x * 64, b0 = blockIdx.y * 64;
  const int tb = tid & 63, iq = tid >> 6;
  for (int ii = iq; ii < 64; ii += 4) {
    int row = inv[i0 + ii];
    t[ii][tb] = lpost2t[(size_t)row * B_ + (b0 + tb)];
  }
  __syncthreads();
  const int ik = tid & 63, bq = tid >> 6;
  for (int bb = bq; bb < 64; bb += 4) {
    out[(size_t)(b0 + bb) * K_ + (i0 + ik)] = -LN2 * t[ik][bb];
  }
}

// ---------------- launch ---------------------------------------------------
extern "C" void kernel_launch(void* const* d_in, const int* in_sizes, int n_in,
                              void* d_out, int out_size, void* d_ws, size_t ws_size,
                              hipStream_t stream) {
  (void)in_sizes; (void)n_in; (void)out_size; (void)ws_size;
  const float* inp = (const float*)d_in[0];
  const int* perm = (const int*)d_in[1];
  float* out = (float*)d_out;

  char* ws = (char*)d_ws;
  const size_t KB = (size_t)K_ * B_;     // elements per [K][B] plane
  const size_t PB = KB * 4;              // bytes per f32 plane
  float*  gx1     = (float*)(ws);
  float*  gy1     = (float*)(ws + PB);
  float*  gx2     = (float*)(ws + PB * 2);
  float*  gy2     = (float*)(ws + PB * 3);
  float*  ls1     = (float*)(ws + PB * 4);
  float*  ls2     = (float*)(ws + PB * 5);
  float*  lpost2t = (float*)(ws + PB * 6);
  int*    inv     = (int*)(ws + PB * 7);        // K ints
  // NII boundary-state buffers: [C_+1][B][8] bf16, ping-pong per decoder/dir
  const size_t SB = (size_t)(C_ + 1) * B_ * 8 * 2;   // ~4.2 MB each
  char* nb = ws + PB * 8;
  ushort_t* S1a = (ushort_t*)(nb);
  ushort_t* S1b = (ushort_t*)(nb + SB);
  ushort_t* T1a = (ushort_t*)(nb + SB * 2);
  ushort_t* T1b = (ushort_t*)(nb + SB * 3);
  ushort_t* S2a = (ushort_t*)(nb + SB * 4);
  ushort_t* S2b = (ushort_t*)(nb + SB * 5);
  ushort_t* T2a = (ushort_t*)(nb + SB * 6);
  ushort_t* T2b = (ushort_t*)(nb + SB * 7);
  unsigned* bar = (unsigned*)(nb + SB * 8);     // barrier cnt/gen
  // total: 8 planes * 6.3 MB + 8 * 4.2 MB + 128 B ~= 84 MB (L3-resident)

  hipMemsetAsync(bar, 0, 128, stream);          // zero barrier state
  k_prep1<<<dim3(K_ / 64, B_ / 64), 256, 0, stream>>>(inp, ls1, gx1, gy1, gy2);
  k_prep2<<<K_, 256, 0, stream>>>(ls1, perm, ls2, inv);

  k_fused<<<C_, 256, 0, stream>>>(gx1, gy1, gx2, gy2, ls1, ls2, perm, inv,
                                  lpost2t, S1a, S1b, T1a, T1b,
                                  S2a, S2b, T2a, T2b, bar, bar + 16);

  k_out<<<dim3(K_ / 64, B_ / 64), 256, 0, stream>>>(lpost2t, inv, out);
}

// Round 10
// 262.281 us; speedup vs baseline: 8.8305x; 8.8305x over previous
//
#include <hip/hip_runtime.h>

// ---------------- problem constants ----------------
constexpr int B_ = 256;        // batch
constexpr int K_ = 6144;       // block length
constexpr int NITER = 6;
constexpr int L_ = 6;          // window valid length
constexpr int W0_ = 32;        // uniform-init warmup (iteration 0)
constexpr int C_ = K_ / L_;    // chunks = 1024
constexpr float LOG2E = 1.4426950408889634f;
constexpr float LN2   = 0.6931471805599453f;

static_assert(K_ % L_ == 0, "");
static_assert((L_ % 2) == 0 && (W0_ % 2) == 0, "");

#if __has_builtin(__builtin_amdgcn_exp2f)
#define EXP2F(x) __builtin_amdgcn_exp2f(x)
#else
#define EXP2F(x) exp2f(x)
#endif
#if __has_builtin(__builtin_amdgcn_logf)
#define LOG2F(x) __builtin_amdgcn_logf(x)
#else
#define LOG2F(x) log2f(x)
#endif
#if __has_builtin(__builtin_amdgcn_rcpf)
#define RCPF(x) __builtin_amdgcn_rcpf(x)
#else
#define RCPF(x) (1.0f / (x))
#endif

// trellis: fb(s,u)=u^s1^s0, nxt(s,u)=(fb<<2)|(s>>1), par(s,u)=u^s1^s2
// Linear-domain with normalized gammas: ghat[u][p] = A_u*B_p, A={1,es} by
// sign of gx (es=2^-|gx|), B likewise (ep=2^-|gy|). Common scale cancels in
// the posterior ratio and renormalized alpha/beta -> equivalent to log-MAP.

__device__ __forceinline__ void gam_lin(float gxv, float gyv, float g[4]) {
  float es = EXP2F(-fabsf(gxv));
  float ep = EXP2F(-fabsf(gyv));
  float fu0 = gxv >= 0.0f ? 1.0f : es;
  float fu1 = gxv >= 0.0f ? es : 1.0f;
  float fp0 = gyv >= 0.0f ? 1.0f : ep;
  float fp1 = gyv >= 0.0f ? ep : 1.0f;
  g[0] = fu0 * fp0; g[1] = fu0 * fp1;
  g[2] = fu1 * fp0; g[3] = fu1 * fp1;
}

__device__ __forceinline__ void step_fwd_lin(float a[8], const float g[4]) {
  float an[8];
#pragma unroll
  for (int sn = 0; sn < 8; ++sn) {
    const int u0 = ((sn >> 2) ^ (sn & 1)) & 1;
    const int p0 = ((sn >> 2) ^ ((sn >> 1) & 1)) & 1;
    an[sn] = a[(sn & 3) * 2] * g[u0 * 2 + p0]
           + a[(sn & 3) * 2 + 1] * g[(u0 ^ 1) * 2 + (p0 ^ 1)];
  }
#pragma unroll
  for (int s = 0; s < 8; ++s) a[s] = an[s];
}

__device__ __forceinline__ void step_bwd_lin(float bt[8], const float g[4]) {
  float bn[8];
#pragma unroll
  for (int s = 0; s < 8; ++s) {
    const int s0 = s & 1, s1b = (s >> 1) & 1, s2b = (s >> 2) & 1;
    const int f0 = s1b ^ s0, q = s1b ^ s2b;
    bn[s] = g[q] * bt[(f0 << 2) | (s >> 1)]
          + g[2 + (q ^ 1)] * bt[((f0 ^ 1) << 2) | (s >> 1)];
  }
#pragma unroll
  for (int s = 0; s < 8; ++s) bt[s] = bn[s];
}

// max-renorm with tiny floor injection: NaN/underflow-proof
__device__ __forceinline__ void renorm_lin(float a[8]) {
  float m = fmaxf(fmaxf(fmaxf(a[0], a[1]), fmaxf(a[2], a[3])),
                  fmaxf(fmaxf(a[4], a[5]), fmaxf(a[6], a[7])));
  float r = RCPF(fmaxf(m, 1e-30f));
#pragma unroll
  for (int s = 0; s < 8; ++s) a[s] = fmaf(a[s], r, 1e-32f);
}

// ---- bf16-packed boundary states (renormalized probs in [1e-32,1]) ------
__device__ __forceinline__ void store8_bf16(unsigned short* p, const float a[8]) {
  unsigned int us[8];
#pragma unroll
  for (int s = 0; s < 8; ++s) {
    unsigned int u = __float_as_uint(a[s]);
    u += 0x7FFFu + ((u >> 16) & 1u);       // round-to-nearest-even
    us[s] = u >> 16;
  }
  uint4 v;
  v.x = us[0] | (us[1] << 16);
  v.y = us[2] | (us[3] << 16);
  v.z = us[4] | (us[5] << 16);
  v.w = us[6] | (us[7] << 16);
  *(uint4*)p = v;
}

__device__ __forceinline__ void load8_bf16(const unsigned short* p, float a[8]) {
  uint4 v = *(const uint4*)p;
  a[0] = __uint_as_float(v.x << 16);
  a[1] = __uint_as_float(v.x & 0xFFFF0000u);
  a[2] = __uint_as_float(v.y << 16);
  a[3] = __uint_as_float(v.y & 0xFFFF0000u);
  a[4] = __uint_as_float(v.z << 16);
  a[5] = __uint_as_float(v.z & 0xFFFF0000u);
  a[6] = __uint_as_float(v.w << 16);
  a[7] = __uint_as_float(v.w & 0xFFFF0000u);
}

// ---------------- k_half: one windowed BCJR half-iteration (linear) -------
// 256-thread blocks = 4 waves = the 4 b-quarters of ONE chunk. wmode 0:
// uniform warmup W0 (it 0); wmode 1: NII boundary state + L warmup steps
// (it 1); wmode 2: pure inheritance (it>=2). S[c] = alpha at c*L_ (bf16,
// renormed); T[c] = beta at c*L_.
// mode 0: scatter extrinsic into other decoder's gx.  mode 1: write lpost.
__global__ __launch_bounds__(256, 4) void k_half(const float* __restrict__ gx,
                                                 const float* __restrict__ gy,
                                                 const float* __restrict__ lsother,
                                                 const int* __restrict__ map,
                                                 float* __restrict__ gxother,
                                                 float* __restrict__ lpost_out,
                                                 const unsigned short* __restrict__ Sread,
                                                 unsigned short* __restrict__ Swrite,
                                                 const unsigned short* __restrict__ Tread,
                                                 unsigned short* __restrict__ Twrite,
                                                 int wmode, int mode) {
  const int tid = threadIdx.x;
  const int c = blockIdx.x;                      // one chunk per block
  const int b = tid;                             // wave = b-quarter
  const int kv = c * L_;
  const int kend = kv + L_;

  // valid-region gamma: load + convert to linear scaled table (cached)
  float gvx[L_];        // log2-domain lsu (needed for extrinsic)
  float gc[L_][4];      // linear scaled gamma table
#pragma unroll
  for (int i = 0; i < L_; ++i) {
    size_t o = (size_t)(kv + i) * B_ + b;
    float x = gx[o], y = gy[o];
    gvx[i] = x;
    gam_lin(x, y, gc[i]);
  }

  // ---------------- forward ----------------
  float a[8];
  if (c == 0) {
    a[0] = 1.0f;
#pragma unroll
    for (int s = 1; s < 8; ++s) a[s] = 0.0f;
  } else if (wmode == 0) {
    int wu = kv < W0_ ? kv : W0_;
    if (kv <= W0_) {                 // warmup reaches position 0: exact init
      a[0] = 1.0f;
#pragma unroll
      for (int s = 1; s < 8; ++s) a[s] = 0.0f;
    } else {
#pragma unroll
      for (int s = 0; s < 8; ++s) a[s] = 1.0f;
    }
    int n = wu, k = kv - wu;
    float cx0, cy0, cx1, cy1;
    if (n > 0) {
      size_t o0 = (size_t)k * B_ + b, o1 = (size_t)(k + 1) * B_ + b;
      cx0 = gx[o0]; cy0 = gy[o0]; cx1 = gx[o1]; cy1 = gy[o1];
    }
    while (n > 0) {
      float nx0, ny0, nx1, ny1;
      if (n > 2) {
        size_t o0 = (size_t)(k + 2) * B_ + b, o1 = (size_t)(k + 3) * B_ + b;
        nx0 = gx[o0]; ny0 = gy[o0]; nx1 = gx[o1]; ny1 = gy[o1];
      }
      float g[4];
      gam_lin(cx0, cy0, g); step_fwd_lin(a, g);
      gam_lin(cx1, cy1, g); step_fwd_lin(a, g);
      renorm_lin(a);
      if (n > 2) { cx0 = nx0; cy0 = ny0; cx1 = nx1; cy1 = ny1; }
      k += 2; n -= 2;
    }
  } else if (wmode == 1) {
    // NII: prev-iter alpha at kv - L_, refreshed by L_ warmup steps.
    float wx[L_], wy[L_];
#pragma unroll
    for (int q = 0; q < L_; ++q) {
      size_t o = (size_t)(kv - L_ + q) * B_ + b;
      wx[q] = gx[o]; wy[q] = gy[o];
    }
    if (c == 1) {                    // warmup starts at position 0: exact init
      a[0] = 1.0f;
#pragma unroll
      for (int s = 1; s < 8; ++s) a[s] = 0.0f;
    } else {
      load8_bf16(&Sread[((size_t)(c - 1) * B_ + b) * 8], a);
    }
#pragma unroll
    for (int q = 0; q < L_; ++q) {
      float g[4];
      gam_lin(wx[q], wy[q], g);
      step_fwd_lin(a, g);
      if (q & 1) renorm_lin(a);
    }
  } else {
    load8_bf16(&Sread[((size_t)c * B_ + b) * 8], a);  // pure inheritance
  }
  // valid region: record alpha, then step (all L steps -> a = alpha(kend))
  float a2d[L_][8];
#pragma unroll
  for (int i = 0; i < L_; ++i) {
#pragma unroll
    for (int s = 0; s < 8; ++s) a2d[i][s] = a[s];
    step_fwd_lin(a, gc[i]);
    if (i & 1) renorm_lin(a);
  }
  if (mode == 0)      // final phase's boundary stores are dead
    store8_bf16(&Swrite[((size_t)(c + 1) * B_ + b) * 8], a);

  // ---------------- backward + posterior ----------------
  float bt[8];
  if (c == C_ - 1) {
#pragma unroll
    for (int s = 0; s < 8; ++s) bt[s] = 1.0f;    // exact tail init (uniform)
  } else if (wmode == 0) {
    int rem = K_ - kend;
    int wub = rem < W0_ ? rem : W0_;
#pragma unroll
    for (int s = 0; s < 8; ++s) bt[s] = 1.0f;
    int n = wub, k = kend + wub - 1;
    float cx0, cy0, cx1, cy1;
    if (n > 0) {
      size_t o0 = (size_t)k * B_ + b, o1 = (size_t)(k - 1) * B_ + b;
      cx0 = gx[o0]; cy0 = gy[o0]; cx1 = gx[o1]; cy1 = gy[o1];
    }
    while (n > 0) {
      float nx0, ny0, nx1, ny1;
      if (n > 2) {
        size_t o0 = (size_t)(k - 2) * B_ + b, o1 = (size_t)(k - 3) * B_ + b;
        nx0 = gx[o0]; ny0 = gy[o0]; nx1 = gx[o1]; ny1 = gy[o1];
      }
      float g[4];
      gam_lin(cx0, cy0, g); step_bwd_lin(bt, g);
      gam_lin(cx1, cy1, g); step_bwd_lin(bt, g);
      renorm_lin(bt);
      if (n > 2) { cx0 = nx0; cy0 = ny0; cx1 = nx1; cy1 = ny1; }
      k -= 2; n -= 2;
    }
  } else if (wmode == 1) {
    float wx[L_], wy[L_];
#pragma unroll
    for (int q = 0; q < L_; ++q) {
      size_t o = (size_t)(kend + L_ - 1 - q) * B_ + b;
      wx[q] = gx[o]; wy[q] = gy[o];
    }
    if (c >= C_ - 2) {                // warmup start >= K_: uniform is exact
#pragma unroll
      for (int s = 0; s < 8; ++s) bt[s] = 1.0f;
    } else {
      load8_bf16(&Tread[((size_t)(c + 2) * B_ + b) * 8], bt);
    }
#pragma unroll
    for (int q = 0; q < L_; ++q) {
      float g[4];
      gam_lin(wx[q], wy[q], g);
      step_bwd_lin(bt, g);
      if (q & 1) renorm_lin(bt);
    }
  } else {
    load8_bf16(&Tread[((size_t)(c + 1) * B_ + b) * 8], bt);  // inheritance
  }
  // valid region, descending: posterior + extrinsic + beta step
#pragma unroll
  for (int ii = 0; ii < L_; ++ii) {
    const int i = L_ - 1 - ii;
    const int kk = kv + i;
    const float* g = gc[i];
    float s00 = 0.0f, s01 = 0.0f, s10 = 0.0f, s11 = 0.0f;
    float bn[8];
#pragma unroll
    for (int s = 0; s < 8; ++s) {
      const int s0 = s & 1, s1b = (s >> 1) & 1, s2b = (s >> 2) & 1;
      const int f0 = s1b ^ s0, q = s1b ^ s2b;
      float b0 = bt[(f0 << 2) | (s >> 1)];
      float b1 = bt[((f0 ^ 1) << 2) | (s >> 1)];
      float m0 = a2d[i][s] * b0;
      float m1 = a2d[i][s] * b1;
      if (q == 0) { s00 += m0; s10 += m1; } else { s01 += m0; s11 += m1; }
      bn[s] = g[q] * b0 + g[2 + (q ^ 1)] * b1;
    }
    float t0 = g[0] * s00 + g[1] * s01;
    float t1 = g[3] * s10 + g[2] * s11;
    float lpost = LOG2F(fmaxf(t0, 1e-37f)) - LOG2F(fmaxf(t1, 1e-37f));
    if (mode == 0) {
      float le = lpost - gvx[i];               // lpost - (ls + la)
      const int j = map[kk];
      const size_t oo = (size_t)j * B_ + b;
      gxother[oo] = lsother[oo] + le;
    } else {
      lpost_out[(size_t)kk * B_ + b] = lpost;
    }
#pragma unroll
    for (int s = 0; s < 8; ++s) bt[s] = bn[s];
    if (ii & 1) renorm_lin(bt);
  }
  if (mode == 0)
    store8_bf16(&Twrite[((size_t)c * B_ + b) * 8], bt);
}

// ---------------- prep: de-interleave + transpose + scale to log2 domain --
__global__ __launch_bounds__(256) void k_prep1(const float* __restrict__ inp,
                                               float* __restrict__ ls1,
                                               float* __restrict__ gx1,
                                               float* __restrict__ gy1,
                                               float* __restrict__ gy2) {
  __shared__ float t[3][64][65];
  const int tid = threadIdx.x;
  const int k0 = blockIdx.x * 64, b0 = blockIdx.y * 64;
  const int tk = tid & 63, tq = tid >> 6;
  for (int bb = tq; bb < 64; bb += 4) {
    size_t base = (size_t)(b0 + bb) * (3 * K_) + 3 * (size_t)(k0 + tk);
    t[0][bb][tk] = inp[base + 0];
    t[1][bb][tk] = inp[base + 1];
    t[2][bb][tk] = inp[base + 2];
  }
  __syncthreads();
  const int tb = tid & 63, kq = tid >> 6;
  for (int kk = kq; kk < 64; kk += 4) {
    size_t o = (size_t)(k0 + kk) * B_ + (b0 + tb);
    float sv = -LOG2E * t[0][tb][kk];
    float p1 = -LOG2E * t[1][tb][kk];
    float p2 = -LOG2E * t[2][tb][kk];
    ls1[o] = sv;
    gx1[o] = sv;          // la=0 initially -> lsu = ls
    gy1[o] = p1;
    gy2[o] = p2;
  }
}

__global__ __launch_bounds__(256) void k_prep2(const float* __restrict__ ls1,
                                               const int* __restrict__ perm,
                                               float* __restrict__ ls2,
                                               int* __restrict__ inv) {
  const int j = blockIdx.x;
  const int b = threadIdx.x;
  const int p = perm[j];
  ls2[(size_t)j * B_ + b] = ls1[(size_t)p * B_ + b];
  if (b == 0) inv[p] = j;
}

// ---------------- output: out[b,i] = -ln2 * lpost2'[inv[i], b] ------------
__global__ __launch_bounds__(256) void k_out(const float* __restrict__ lpost2t,
                                             const int* __restrict__ inv,
                                             float* __restrict__ out) {
  __shared__ float t[64][65];
  const int tid = threadIdx.x;
  const int i0 = blockIdx.x * 64, b0 = blockIdx.y * 64;
  const int tb = tid & 63, iq = tid >> 6;
  for (int ii = iq; ii < 64; ii += 4) {
    int row = inv[i0 + ii];
    t[ii][tb] = lpost2t[(size_t)row * B_ + (b0 + tb)];
  }
  __syncthreads();
  const int ik = tid & 63, bq = tid >> 6;
  for (int bb = bq; bb < 64; bb += 4) {
    out[(size_t)(b0 + bb) * K_ + (i0 + ik)] = -LN2 * t[ik][bb];
  }
}

// ---------------- launch ---------------------------------------------------
extern "C" void kernel_launch(void* const* d_in, const int* in_sizes, int n_in,
                              void* d_out, int out_size, void* d_ws, size_t ws_size,
                              hipStream_t stream) {
  (void)in_sizes; (void)n_in; (void)out_size; (void)ws_size;
  const float* inp = (const float*)d_in[0];
  const int* perm = (const int*)d_in[1];
  float* out = (float*)d_out;

  char* ws = (char*)d_ws;
  const size_t KB = (size_t)K_ * B_;     // elements per [K][B] plane
  const size_t PB = KB * 4;              // bytes per f32 plane
  float*  gx1     = (float*)(ws);
  float*  gy1     = (float*)(ws + PB);
  float*  gx2     = (float*)(ws + PB * 2);
  float*  gy2     = (float*)(ws + PB * 3);
  float*  ls1     = (float*)(ws + PB * 4);
  float*  ls2     = (float*)(ws + PB * 5);
  float*  lpost2t = (float*)(ws + PB * 6);
  int*    inv     = (int*)(ws + PB * 7);        // K ints
  // NII boundary-state buffers: [C_+1][B][8] bf16, ping-pong per decoder/dir
  const size_t SB = (size_t)(C_ + 1) * B_ * 8 * 2;   // ~4.2 MB each
  char* nb = ws + PB * 8;
  unsigned short* S1[2] = {(unsigned short*)(nb),          (unsigned short*)(nb + SB)};
  unsigned short* T1[2] = {(unsigned short*)(nb + SB * 2), (unsigned short*)(nb + SB * 3)};
  unsigned short* S2[2] = {(unsigned short*)(nb + SB * 4), (unsigned short*)(nb + SB * 5)};
  unsigned short* T2[2] = {(unsigned short*)(nb + SB * 6), (unsigned short*)(nb + SB * 7)};
  // total: 8 planes * 6.3 MB + 8 * 4.2 MB ~= 84 MB (L3-resident)

  k_prep1<<<dim3(K_ / 64, B_ / 64), 256, 0, stream>>>(inp, ls1, gx1, gy1, gy2);
  k_prep2<<<K_, 256, 0, stream>>>(ls1, perm, ls2, inv);

  for (int it = 0; it < NITER; ++it) {
    const int pr = it & 1, pw = pr ^ 1;   // read prev-iter buffer, write other
    const int wm = (it == 0) ? 0 : (it == 1 ? 1 : 2);
    k_half<<<C_, 256, 0, stream>>>(gx1, gy1, ls2, inv, gx2, lpost2t,
                                   S1[pr], S1[pw], T1[pr], T1[pw],
                                   wm, 0);
    k_half<<<C_, 256, 0, stream>>>(gx2, gy2, ls1, perm, gx1, lpost2t,
                                   S2[pr], S2[pw], T2[pr], T2[pw],
                                   wm, (it == NITER - 1) ? 1 : 0);
  }
  k_out<<<dim3(K_ / 64, B_ / 64), 256, 0, stream>>>(lpost2t, inv, out);
}

// Round 11
// 256.201 us; speedup vs baseline: 9.0401x; 1.0237x over previous
//
#include <hip/hip_runtime.h>

// ---------------- problem constants ----------------
constexpr int B_ = 256;        // batch
constexpr int K_ = 6144;       // block length
constexpr int NITER = 6;
constexpr int L_ = 6;          // window valid length
constexpr int W0_ = 32;        // uniform-init warmup (iteration 0)
constexpr int C_ = K_ / L_;    // chunks = 1024
constexpr float LOG2E = 1.4426950408889634f;
constexpr float LN2   = 0.6931471805599453f;

static_assert(K_ % L_ == 0, "");
static_assert((L_ % 2) == 0 && (W0_ % 2) == 0, "");

#if __has_builtin(__builtin_amdgcn_exp2f)
#define EXP2F(x) __builtin_amdgcn_exp2f(x)
#else
#define EXP2F(x) exp2f(x)
#endif
#if __has_builtin(__builtin_amdgcn_logf)
#define LOG2F(x) __builtin_amdgcn_logf(x)
#else
#define LOG2F(x) log2f(x)
#endif
#if __has_builtin(__builtin_amdgcn_rcpf)
#define RCPF(x) __builtin_amdgcn_rcpf(x)
#else
#define RCPF(x) (1.0f / (x))
#endif

// trellis: fb(s,u)=u^s1^s0, nxt(s,u)=(fb<<2)|(s>>1), par(s,u)=u^s1^s2
// Linear-domain with normalized gammas: ghat[u][p] = A_u*B_p, A={1,es} by
// sign of gx (es=2^-|gx|), B likewise (ep=2^-|gy|). Common scale cancels in
// the posterior ratio and renormalized alpha/beta -> equivalent to log-MAP.

__device__ __forceinline__ void gam_lin(float gxv, float gyv, float g[4]) {
  float es = EXP2F(-fabsf(gxv));
  float ep = EXP2F(-fabsf(gyv));
  float fu0 = gxv >= 0.0f ? 1.0f : es;
  float fu1 = gxv >= 0.0f ? es : 1.0f;
  float fp0 = gyv >= 0.0f ? 1.0f : ep;
  float fp1 = gyv >= 0.0f ? ep : 1.0f;
  g[0] = fu0 * fp0; g[1] = fu0 * fp1;
  g[2] = fu1 * fp0; g[3] = fu1 * fp1;
}

__device__ __forceinline__ void step_fwd_lin(float a[8], const float g[4]) {
  float an[8];
#pragma unroll
  for (int sn = 0; sn < 8; ++sn) {
    const int u0 = ((sn >> 2) ^ (sn & 1)) & 1;
    const int p0 = ((sn >> 2) ^ ((sn >> 1) & 1)) & 1;
    an[sn] = a[(sn & 3) * 2] * g[u0 * 2 + p0]
           + a[(sn & 3) * 2 + 1] * g[(u0 ^ 1) * 2 + (p0 ^ 1)];
  }
#pragma unroll
  for (int s = 0; s < 8; ++s) a[s] = an[s];
}

__device__ __forceinline__ void step_bwd_lin(float bt[8], const float g[4]) {
  float bn[8];
#pragma unroll
  for (int s = 0; s < 8; ++s) {
    const int s0 = s & 1, s1b = (s >> 1) & 1, s2b = (s >> 2) & 1;
    const int f0 = s1b ^ s0, q = s1b ^ s2b;
    bn[s] = g[q] * bt[(f0 << 2) | (s >> 1)]
          + g[2 + (q ^ 1)] * bt[((f0 ^ 1) << 2) | (s >> 1)];
  }
#pragma unroll
  for (int s = 0; s < 8; ++s) bt[s] = bn[s];
}

// max-renorm with tiny floor injection: NaN/underflow-proof
__device__ __forceinline__ void renorm_lin(float a[8]) {
  float m = fmaxf(fmaxf(fmaxf(a[0], a[1]), fmaxf(a[2], a[3])),
                  fmaxf(fmaxf(a[4], a[5]), fmaxf(a[6], a[7])));
  float r = RCPF(fmaxf(m, 1e-30f));
#pragma unroll
  for (int s = 0; s < 8; ++s) a[s] = fmaf(a[s], r, 1e-32f);
}

// ---- bf16-packed boundary states (renormalized probs in [1e-32,1]) ------
__device__ __forceinline__ void store8_bf16(unsigned short* p, const float a[8]) {
  unsigned int us[8];
#pragma unroll
  for (int s = 0; s < 8; ++s) {
    unsigned int u = __float_as_uint(a[s]);
    u += 0x7FFFu + ((u >> 16) & 1u);       // round-to-nearest-even
    us[s] = u >> 16;
  }
  uint4 v;
  v.x = us[0] | (us[1] << 16);
  v.y = us[2] | (us[3] << 16);
  v.z = us[4] | (us[5] << 16);
  v.w = us[6] | (us[7] << 16);
  *(uint4*)p = v;
}

__device__ __forceinline__ void unpack8_bf16(uint4 v, float a[8]) {
  a[0] = __uint_as_float(v.x << 16);
  a[1] = __uint_as_float(v.x & 0xFFFF0000u);
  a[2] = __uint_as_float(v.y << 16);
  a[3] = __uint_as_float(v.y & 0xFFFF0000u);
  a[4] = __uint_as_float(v.z << 16);
  a[5] = __uint_as_float(v.z & 0xFFFF0000u);
  a[6] = __uint_as_float(v.w << 16);
  a[7] = __uint_as_float(v.w & 0xFFFF0000u);
}

// ---------------- k_half: one windowed BCJR half-iteration (linear) -------
// 256-thread blocks = 4 waves = the 4 b-quarters of ONE chunk. wmode 0:
// uniform warmup W0 (it 0); wmode 1: NII boundary state + L warmup steps
// (it 1); wmode 2: pure inheritance (it>=2). S[c] = alpha at c*L_ (bf16,
// renormed); T[c] = beta at c*L_. ALL independent loads are hoisted to
// kernel entry for memory-level parallelism (latency-bound otherwise).
// mode 0: scatter extrinsic into other decoder's gx.  mode 1: write lpost.
// wrS 0: skip dead boundary-state stores (last iteration).
__global__ __launch_bounds__(256, 4) void k_half(const float* __restrict__ gx,
                                                 const float* __restrict__ gy,
                                                 const float* __restrict__ lsother,
                                                 const int* __restrict__ map,
                                                 float* __restrict__ gxother,
                                                 float* __restrict__ lpost_out,
                                                 const unsigned short* __restrict__ Sread,
                                                 unsigned short* __restrict__ Swrite,
                                                 const unsigned short* __restrict__ Tread,
                                                 unsigned short* __restrict__ Twrite,
                                                 int wmode, int mode, int wrS) {
  const int tid = threadIdx.x;
  const int c = blockIdx.x;                      // one chunk per block
  const int b = tid;                             // wave = b-quarter
  const int kv = c * L_;
  const int kend = kv + L_;

  // ---- issue ALL independent loads upfront ----
  float gvx[L_], rgy[L_];
#pragma unroll
  for (int i = 0; i < L_; ++i) {
    size_t o = (size_t)(kv + i) * B_ + b;
    gvx[i] = gx[o];
    rgy[i] = gy[o];
  }
  float lsr[L_];
  int jmap[L_];
  if (mode == 0) {
#pragma unroll
    for (int i = 0; i < L_; ++i) jmap[i] = map[kv + i];   // block-uniform
#pragma unroll
    for (int i = 0; i < L_; ++i)
      lsr[i] = lsother[(size_t)jmap[i] * B_ + b];
  }
  uint4 sraw, traw;
  float wfx[L_], wfy[L_], wbx[L_], wby[L_];
  if (wmode == 1) {
    if (c > 1)
      sraw = *(const uint4*)&Sread[((size_t)(c - 1) * B_ + b) * 8];
    if (c < C_ - 2)
      traw = *(const uint4*)&Tread[((size_t)(c + 2) * B_ + b) * 8];
    if (c > 0) {
#pragma unroll
      for (int q = 0; q < L_; ++q) {
        size_t o = (size_t)(kv - L_ + q) * B_ + b;
        wfx[q] = gx[o]; wfy[q] = gy[o];
      }
    }
    if (c < C_ - 1) {
#pragma unroll
      for (int q = 0; q < L_; ++q) {
        size_t o = (size_t)(kend + L_ - 1 - q) * B_ + b;
        wbx[q] = gx[o]; wby[q] = gy[o];
      }
    }
  } else if (wmode == 2) {
    if (c > 0)
      sraw = *(const uint4*)&Sread[((size_t)c * B_ + b) * 8];
    if (c < C_ - 1)
      traw = *(const uint4*)&Tread[((size_t)(c + 1) * B_ + b) * 8];
  }

  // ---- convert valid gamma (gvx kept: needed for extrinsic) ----
  float gc[L_][4];
#pragma unroll
  for (int i = 0; i < L_; ++i) gam_lin(gvx[i], rgy[i], gc[i]);

  // ---------------- forward ----------------
  float a[8];
  if (c == 0) {
    a[0] = 1.0f;
#pragma unroll
    for (int s = 1; s < 8; ++s) a[s] = 0.0f;
  } else if (wmode == 0) {
    int wu = kv < W0_ ? kv : W0_;
    if (kv <= W0_) {                 // warmup reaches position 0: exact init
      a[0] = 1.0f;
#pragma unroll
      for (int s = 1; s < 8; ++s) a[s] = 0.0f;
    } else {
#pragma unroll
      for (int s = 0; s < 8; ++s) a[s] = 1.0f;
    }
    int n = wu, k = kv - wu;
    float cx0, cy0, cx1, cy1;
    if (n > 0) {
      size_t o0 = (size_t)k * B_ + b, o1 = (size_t)(k + 1) * B_ + b;
      cx0 = gx[o0]; cy0 = gy[o0]; cx1 = gx[o1]; cy1 = gy[o1];
    }
    while (n > 0) {
      float nx0, ny0, nx1, ny1;
      if (n > 2) {
        size_t o0 = (size_t)(k + 2) * B_ + b, o1 = (size_t)(k + 3) * B_ + b;
        nx0 = gx[o0]; ny0 = gy[o0]; nx1 = gx[o1]; ny1 = gy[o1];
      }
      float g[4];
      gam_lin(cx0, cy0, g); step_fwd_lin(a, g);
      gam_lin(cx1, cy1, g); step_fwd_lin(a, g);
      renorm_lin(a);
      if (n > 2) { cx0 = nx0; cy0 = ny0; cx1 = nx1; cy1 = ny1; }
      k += 2; n -= 2;
    }
  } else if (wmode == 1) {
    if (c == 1) {                    // warmup starts at position 0: exact init
      a[0] = 1.0f;
#pragma unroll
      for (int s = 1; s < 8; ++s) a[s] = 0.0f;
    } else {
      unpack8_bf16(sraw, a);
    }
#pragma unroll
    for (int q = 0; q < L_; ++q) {
      float g[4];
      gam_lin(wfx[q], wfy[q], g);
      step_fwd_lin(a, g);
      if (q & 1) renorm_lin(a);
    }
  } else {
    unpack8_bf16(sraw, a);           // pure inheritance (c>0 here)
  }
  // valid region: record alpha, then step (all L steps -> a = alpha(kend))
  float a2d[L_][8];
#pragma unroll
  for (int i = 0; i < L_; ++i) {
#pragma unroll
    for (int s = 0; s < 8; ++s) a2d[i][s] = a[s];
    step_fwd_lin(a, gc[i]);
    if (i & 1) renorm_lin(a);
  }
  if (wrS)
    store8_bf16(&Swrite[((size_t)(c + 1) * B_ + b) * 8], a);

  // ---------------- backward + posterior ----------------
  float bt[8];
  if (c == C_ - 1) {
#pragma unroll
    for (int s = 0; s < 8; ++s) bt[s] = 1.0f;    // exact tail init (uniform)
  } else if (wmode == 0) {
    int rem = K_ - kend;
    int wub = rem < W0_ ? rem : W0_;
#pragma unroll
    for (int s = 0; s < 8; ++s) bt[s] = 1.0f;
    int n = wub, k = kend + wub - 1;
    float cx0, cy0, cx1, cy1;
    if (n > 0) {
      size_t o0 = (size_t)k * B_ + b, o1 = (size_t)(k - 1) * B_ + b;
      cx0 = gx[o0]; cy0 = gy[o0]; cx1 = gx[o1]; cy1 = gy[o1];
    }
    while (n > 0) {
      float nx0, ny0, nx1, ny1;
      if (n > 2) {
        size_t o0 = (size_t)(k - 2) * B_ + b, o1 = (size_t)(k - 3) * B_ + b;
        nx0 = gx[o0]; ny0 = gy[o0]; nx1 = gx[o1]; ny1 = gy[o1];
      }
      float g[4];
      gam_lin(cx0, cy0, g); step_bwd_lin(bt, g);
      gam_lin(cx1, cy1, g); step_bwd_lin(bt, g);
      renorm_lin(bt);
      if (n > 2) { cx0 = nx0; cy0 = ny0; cx1 = nx1; cy1 = ny1; }
      k -= 2; n -= 2;
    }
  } else if (wmode == 1) {
    if (c >= C_ - 2) {                // warmup start >= K_: uniform is exact
#pragma unroll
      for (int s = 0; s < 8; ++s) bt[s] = 1.0f;
    } else {
      unpack8_bf16(traw, bt);
    }
#pragma unroll
    for (int q = 0; q < L_; ++q) {
      float g[4];
      gam_lin(wbx[q], wby[q], g);
      step_bwd_lin(bt, g);
      if (q & 1) renorm_lin(bt);
    }
  } else {
    unpack8_bf16(traw, bt);          // pure inheritance (c<C_-1 here)
  }
  // valid region, descending: posterior + extrinsic + beta step
#pragma unroll
  for (int ii = 0; ii < L_; ++ii) {
    const int i = L_ - 1 - ii;
    const int kk = kv + i;
    const float* g = gc[i];
    float s00 = 0.0f, s01 = 0.0f, s10 = 0.0f, s11 = 0.0f;
    float bn[8];
#pragma unroll
    for (int s = 0; s < 8; ++s) {
      const int s0 = s & 1, s1b = (s >> 1) & 1, s2b = (s >> 2) & 1;
      const int f0 = s1b ^ s0, q = s1b ^ s2b;
      float b0 = bt[(f0 << 2) | (s >> 1)];
      float b1 = bt[((f0 ^ 1) << 2) | (s >> 1)];
      float m0 = a2d[i][s] * b0;
      float m1 = a2d[i][s] * b1;
      if (q == 0) { s00 += m0; s10 += m1; } else { s01 += m0; s11 += m1; }
      bn[s] = g[q] * b0 + g[2 + (q ^ 1)] * b1;
    }
    float t0 = g[0] * s00 + g[1] * s01;
    float t1 = g[3] * s10 + g[2] * s11;
    float lpost = LOG2F(fmaxf(t0, 1e-37f)) - LOG2F(fmaxf(t1, 1e-37f));
    if (mode == 0) {
      float le = lpost - gvx[i];               // lpost - (ls + la)
      const size_t oo = (size_t)jmap[i] * B_ + b;
      gxother[oo] = lsr[i] + le;
    } else {
      lpost_out[(size_t)kk * B_ + b] = lpost;
    }
#pragma unroll
    for (int s = 0; s < 8; ++s) bt[s] = bn[s];
    if (ii & 1) renorm_lin(bt);
  }
  if (wrS)
    store8_bf16(&Twrite[((size_t)c * B_ + b) * 8], bt);
}

// ---------------- prep: de-interleave + transpose + scale to log2 domain --
__global__ __launch_bounds__(256) void k_prep1(const float* __restrict__ inp,
                                               float* __restrict__ ls1,
                                               float* __restrict__ gx1,
                                               float* __restrict__ gy1,
                                               float* __restrict__ gy2) {
  __shared__ float t[3][64][65];
  const int tid = threadIdx.x;
  const int k0 = blockIdx.x * 64, b0 = blockIdx.y * 64;
  const int tk = tid & 63, tq = tid >> 6;
  for (int bb = tq; bb < 64; bb += 4) {
    size_t base = (size_t)(b0 + bb) * (3 * K_) + 3 * (size_t)(k0 + tk);
    t[0][bb][tk] = inp[base + 0];
    t[1][bb][tk] = inp[base + 1];
    t[2][bb][tk] = inp[base + 2];
  }
  __syncthreads();
  const int tb = tid & 63, kq = tid >> 6;
  for (int kk = kq; kk < 64; kk += 4) {
    size_t o = (size_t)(k0 + kk) * B_ + (b0 + tb);
    float sv = -LOG2E * t[0][tb][kk];
    float p1 = -LOG2E * t[1][tb][kk];
    float p2 = -LOG2E * t[2][tb][kk];
    ls1[o] = sv;
    gx1[o] = sv;          // la=0 initially -> lsu = ls
    gy1[o] = p1;
    gy2[o] = p2;
  }
}

__global__ __launch_bounds__(256) void k_prep2(const float* __restrict__ ls1,
                                               const int* __restrict__ perm,
                                               float* __restrict__ ls2,
                                               int* __restrict__ inv) {
  const int j = blockIdx.x;
  const int b = threadIdx.x;
  const int p = perm[j];
  ls2[(size_t)j * B_ + b] = ls1[(size_t)p * B_ + b];
  if (b == 0) inv[p] = j;
}

// ---------------- output: out[b,i] = -ln2 * lpost2'[inv[i], b] ------------
__global__ __launch_bounds__(256) void k_out(const float* __restrict__ lpost2t,
                                             const int* __restrict__ inv,
                                             float* __restrict__ out) {
  __shared__ float t[64][65];
  const int tid = threadIdx.x;
  const int i0 = blockIdx.x * 64, b0 = blockIdx.y * 64;
  const int tb = tid & 63, iq = tid >> 6;
  for (int ii = iq; ii < 64; ii += 4) {
    int row = inv[i0 + ii];
    t[ii][tb] = lpost2t[(size_t)row * B_ + (b0 + tb)];
  }
  __syncthreads();
  const int ik = tid & 63, bq = tid >> 6;
  for (int bb = bq; bb < 64; bb += 4) {
    out[(size_t)(b0 + bb) * K_ + (i0 + ik)] = -LN2 * t[ik][bb];
  }
}

// ---------------- launch ---------------------------------------------------
extern "C" void kernel_launch(void* const* d_in, const int* in_sizes, int n_in,
                              void* d_out, int out_size, void* d_ws, size_t ws_size,
                              hipStream_t stream) {
  (void)in_sizes; (void)n_in; (void)out_size; (void)ws_size;
  const float* inp = (const float*)d_in[0];
  const int* perm = (const int*)d_in[1];
  float* out = (float*)d_out;

  char* ws = (char*)d_ws;
  const size_t KB = (size_t)K_ * B_;     // elements per [K][B] plane
  const size_t PB = KB * 4;              // bytes per f32 plane
  float*  gx1     = (float*)(ws);
  float*  gy1     = (float*)(ws + PB);
  float*  gx2     = (float*)(ws + PB * 2);
  float*  gy2     = (float*)(ws + PB * 3);
  float*  ls1     = (float*)(ws + PB * 4);
  float*  ls2     = (float*)(ws + PB * 5);
  float*  lpost2t = (float*)(ws + PB * 6);
  int*    inv     = (int*)(ws + PB * 7);        // K ints
  // NII boundary-state buffers: [C_+1][B][8] bf16, ping-pong per decoder/dir
  const size_t SB = (size_t)(C_ + 1) * B_ * 8 * 2;   // ~4.2 MB each
  char* nb = ws + PB * 8;
  unsigned short* S1[2] = {(unsigned short*)(nb),          (unsigned short*)(nb + SB)};
  unsigned short* T1[2] = {(unsigned short*)(nb + SB * 2), (unsigned short*)(nb + SB * 3)};
  unsigned short* S2[2] = {(unsigned short*)(nb + SB * 4), (unsigned short*)(nb + SB * 5)};
  unsigned short* T2[2] = {(unsigned short*)(nb + SB * 6), (unsigned short*)(nb + SB * 7)};
  // total: 8 planes * 6.3 MB + 8 * 4.2 MB ~= 84 MB (L3-resident)

  k_prep1<<<dim3(K_ / 64, B_ / 64), 256, 0, stream>>>(inp, ls1, gx1, gy1, gy2);
  k_prep2<<<K_, 256, 0, stream>>>(ls1, perm, ls2, inv);

  for (int it = 0; it < NITER; ++it) {
    const int pr = it & 1, pw = pr ^ 1;   // read prev-iter buffer, write other
    const int wm = (it == 0) ? 0 : (it == 1 ? 1 : 2);
    const int wrS = (it != NITER - 1) ? 1 : 0;
    k_half<<<C_, 256, 0, stream>>>(gx1, gy1, ls2, inv, gx2, lpost2t,
                                   S1[pr], S1[pw], T1[pr], T1[pw],
                                   wm, 0, wrS);
    k_half<<<C_, 256, 0, stream>>>(gx2, gy2, ls1, perm, gx1, lpost2t,
                                   S2[pr], S2[pw], T2[pr], T2[pw],
                                   wm, (it == NITER - 1) ? 1 : 0, wrS);
  }
  k_out<<<dim3(K_ / 64, B_ / 64), 256, 0, stream>>>(lpost2t, inv, out);
}